// Round 5
// baseline (614.490 us; speedup 1.0000x reference)
//
#include <hip/hip_runtime.h>
#include <hip/hip_bf16.h>

#define NB 256
#define NR 100
#define ND 6168
#define DP 6176            // ND padded to multiple of 32 (386 k-steps of 16)
#define NH 128
#define NC 100
#define KG 193             // k-steps (K=16) per K-group; 2 groups x 193 = 386

typedef __attribute__((ext_vector_type(8)))  __bf16 bf16x8;
typedef __attribute__((ext_vector_type(16))) float  f32x16;
typedef __attribute__((ext_vector_type(4)))  float  f32x4;
typedef __attribute__((ext_vector_type(4)))  int    i32x4;
typedef __attribute__((ext_vector_type(4)))  unsigned int u32x4;

// ---------- prep: W1 (ND,NH) f32 -> W1T (NH, DP) bf16, zero-padded ----------
__global__ void prep_w1t(const float* __restrict__ W1, __hip_bfloat16* __restrict__ W1T) {
  __shared__ float tile[32][NH + 1];
  const int d0 = blockIdx.x * 32;
  const int t = threadIdx.x;
#pragma unroll
  for (int p = 0; p < 16; ++p) {
    int idx = p * 256 + t;
    int dd = idx >> 7;
    int h  = idx & 127;
    int d  = d0 + dd;
    tile[dd][h] = (d < ND) ? W1[d * NH + h] : 0.f;
  }
  __syncthreads();
#pragma unroll
  for (int p = 0; p < 16; ++p) {
    int idx = p * 256 + t;
    int h  = idx >> 5;
    int dd = idx & 31;
    W1T[h * DP + d0 + dd] = __float2bfloat16(tile[dd][h]);
  }
}

// ---------- main fused kernel: one block per b, 512 threads (8 waves) ----------
// Waves 0-3: K-group 0 (ksteps 0..192), rows (w&3)*32. Waves 4-7: K-group 1.
// No barriers in the K-loop: fragments built directly from global memory.
// LDS: [0,12352) xpair; [12352,77888) combine (16 x 4KB); [77888,79936) hpart;
//      [79936,80448) hbar.
__launch_bounds__(512, 2)
__global__ void fused_main(const int* __restrict__ x,
                           const int* __restrict__ noise,
                           const __hip_bfloat16* __restrict__ W1T,
                           const float* __restrict__ b1,
                           const float* __restrict__ W2,
                           const float* __restrict__ b2,
                           float* __restrict__ out) {
  __shared__ __align__(16) char lds[80448];
  unsigned int* xpair = (unsigned int*)lds;            // [3088] u32
  char*  cb    = lds + 12352;                          // combine region
  float* hpart = (float*)(lds + 77888);                // [4][128]
  float* hbarv = (float*)(lds + 79936);                // [128]

  const int tid = threadIdx.x;
  const int l   = tid & 63;
  const int w   = tid >> 6;      // 0..7
  const int g   = w >> 2;        // K-group
  const int wr  = w & 3;         // row-group (rows wr*32 .. wr*32+31)
  const int kq  = l >> 5;        // k-octet within 16-wide kstep
  const int kq8 = kq * 8;
  const int ln  = l & 31;
  const int b   = blockIdx.x;

  // clamped row (rows >= NR read row NR-1; garbage masked in epilogue)
  const int rc = min(wr * 32 + ln, NR - 1);
  const int* nrow = noise + (size_t)b * NR * ND + (size_t)rc * ND;
  const __hip_bfloat16* wb0 = W1T + (size_t)(ln)      * DP;
  const __hip_bfloat16* wb1 = W1T + (size_t)(32 + ln) * DP;
  const __hip_bfloat16* wb2 = W1T + (size_t)(64 + ln) * DP;
  const __hip_bfloat16* wb3 = W1T + (size_t)(96 + ln) * DP;

  f32x16 acc0 = {}, acc1 = {}, acc2 = {}, acc3 = {};

  struct Batch {            // 2 ksteps (K=32): all members statically accessed
    i32x4 a0, a1, a2, a3;                      // noise: kstep0 (a0,a1), kstep1
    i32x4 b00, b01, b02, b03, b10, b11, b12, b13;  // W1T frags x4, 2 ksteps
    u32x4 x0, x1;                               // xpair words
  };

  auto LOADB2 = [&](int s, Batch& R) {
    const int k0 = s * 16 + kq8;
    const int k1 = k0 + 16;
    const int k0a = min(k0, ND - 8);     // clamp: only final kstep; B=0 there
    const int k1a = min(k1, ND - 8);
    R.a0 = *(const i32x4*)(nrow + k0a);
    R.a1 = *(const i32x4*)(nrow + k0a + 4);
    R.a2 = *(const i32x4*)(nrow + k1a);
    R.a3 = *(const i32x4*)(nrow + k1a + 4);
    R.b00 = *(const i32x4*)(wb0 + k0);
    R.b01 = *(const i32x4*)(wb1 + k0);
    R.b02 = *(const i32x4*)(wb2 + k0);
    R.b03 = *(const i32x4*)(wb3 + k0);
    R.b10 = *(const i32x4*)(wb0 + k1);
    R.b11 = *(const i32x4*)(wb1 + k1);
    R.b12 = *(const i32x4*)(wb2 + k1);
    R.b13 = *(const i32x4*)(wb3 + k1);
    R.x0 = *(const u32x4*)(xpair + (k0 >> 1));
    R.x1 = *(const u32x4*)(xpair + (k1 >> 1));
  };

  auto PACK = [&](const i32x4& p, const i32x4& q, const u32x4& xp) -> bf16x8 {
    unsigned p0 = (((unsigned)p[0] | ((unsigned)p[1] << 16)) ^ xp[0]) * 0x3F80u;
    unsigned p1 = (((unsigned)p[2] | ((unsigned)p[3] << 16)) ^ xp[1]) * 0x3F80u;
    unsigned p2 = (((unsigned)q[0] | ((unsigned)q[1] << 16)) ^ xp[2]) * 0x3F80u;
    unsigned p3 = (((unsigned)q[2] | ((unsigned)q[3] << 16)) ^ xp[3]) * 0x3F80u;
    u32x4 pk = {p0, p1, p2, p3};
    return *(bf16x8*)&pk;
  };

  auto CONSUME2 = [&](const Batch& R) {
    bf16x8 af0 = PACK(R.a0, R.a1, R.x0);
    acc0 = __builtin_amdgcn_mfma_f32_32x32x16_bf16(af0, *(const bf16x8*)&R.b00, acc0, 0, 0, 0);
    acc1 = __builtin_amdgcn_mfma_f32_32x32x16_bf16(af0, *(const bf16x8*)&R.b01, acc1, 0, 0, 0);
    acc2 = __builtin_amdgcn_mfma_f32_32x32x16_bf16(af0, *(const bf16x8*)&R.b02, acc2, 0, 0, 0);
    acc3 = __builtin_amdgcn_mfma_f32_32x32x16_bf16(af0, *(const bf16x8*)&R.b03, acc3, 0, 0, 0);
    bf16x8 af1 = PACK(R.a2, R.a3, R.x1);
    acc0 = __builtin_amdgcn_mfma_f32_32x32x16_bf16(af1, *(const bf16x8*)&R.b10, acc0, 0, 0, 0);
    acc1 = __builtin_amdgcn_mfma_f32_32x32x16_bf16(af1, *(const bf16x8*)&R.b11, acc1, 0, 0, 0);
    acc2 = __builtin_amdgcn_mfma_f32_32x32x16_bf16(af1, *(const bf16x8*)&R.b12, acc2, 0, 0, 0);
    acc3 = __builtin_amdgcn_mfma_f32_32x32x16_bf16(af1, *(const bf16x8*)&R.b13, acc3, 0, 0, 0);
  };

  // ---- prologue: pack x into paired-bf16-slot bits ----
  {
    const int* xb = x + b * ND;
    for (int i = tid; i < DP / 2; i += 512) {
      unsigned p = 0;
      if (2 * i + 1 < ND) {
        int2 v = *(const int2*)(xb + 2 * i);
        p = ((unsigned)v.x & 1u) | (((unsigned)v.y & 1u) << 16);
      }
      xpair[i] = p;
    }
  }
  __syncthreads();   // the ONLY barrier before the K-loop ends

  // ---- barrier-free K-loop: 96 batches of 2 ksteps + 1 tail kstep ----
  const int s0 = g * KG;
  Batch RA, RB;
  LOADB2(s0, RA);
  LOADB2(s0 + 2, RB);
  int sb = s0 + 4;
#pragma unroll 1
  for (int it = 0; it < 47; ++it) {
    CONSUME2(RA); LOADB2(sb, RA);
    CONSUME2(RB); LOADB2(sb + 2, RB);
    sb += 4;
  }
  CONSUME2(RA);      // ksteps s0+188,189
  CONSUME2(RB);      // ksteps s0+190,191
  {                  // tail kstep s0+192
    const int k0 = (s0 + 192) * 16 + kq8;
    const int k0a = min(k0, ND - 8);
    i32x4 ta0 = *(const i32x4*)(nrow + k0a);
    i32x4 ta1 = *(const i32x4*)(nrow + k0a + 4);
    i32x4 tb0 = *(const i32x4*)(wb0 + k0);
    i32x4 tb1 = *(const i32x4*)(wb1 + k0);
    i32x4 tb2 = *(const i32x4*)(wb2 + k0);
    i32x4 tb3 = *(const i32x4*)(wb3 + k0);
    u32x4 tx  = *(const u32x4*)(xpair + (k0 >> 1));
    bf16x8 af = PACK(ta0, ta1, tx);
    acc0 = __builtin_amdgcn_mfma_f32_32x32x16_bf16(af, *(const bf16x8*)&tb0, acc0, 0, 0, 0);
    acc1 = __builtin_amdgcn_mfma_f32_32x32x16_bf16(af, *(const bf16x8*)&tb1, acc1, 0, 0, 0);
    acc2 = __builtin_amdgcn_mfma_f32_32x32x16_bf16(af, *(const bf16x8*)&tb2, acc2, 0, 0, 0);
    acc3 = __builtin_amdgcn_mfma_f32_32x32x16_bf16(af, *(const bf16x8*)&tb3, acc3, 0, 0, 0);
  }

  // ---- epilogue ----
  __syncthreads();
  // combine the two K-groups (swizzled LDS offsets: conflict-free b128)
#define COFF(f, t) ((((wr) * 4 + (f)) << 12) + (((l * 64) + (t) * 16) ^ ((l & 7) << 4)))
#define STORE_ACC(f, A) do { _Pragma("unroll") for (int t = 0; t < 4; ++t) { \
    f32x4 qv = {(A)[4*t], (A)[4*t+1], (A)[4*t+2], (A)[4*t+3]}; \
    *(f32x4*)(cb + COFF(f, t)) = qv; } } while (0)
#define ADD_ACC(f, A) do { _Pragma("unroll") for (int t = 0; t < 4; ++t) { \
    f32x4 qv = *(const f32x4*)(cb + COFF(f, t)); \
    (A)[4*t] += qv[0]; (A)[4*t+1] += qv[1]; (A)[4*t+2] += qv[2]; (A)[4*t+3] += qv[3]; } } while (0)

  if (g == 1) {
    STORE_ACC(0, acc0); STORE_ACC(1, acc1); STORE_ACC(2, acc2); STORE_ACC(3, acc3);
  }
  __syncthreads();
  if (g == 0) {
    ADD_ACC(0, acc0); ADD_ACC(1, acc1); ADD_ACC(2, acc2); ADD_ACC(3, acc3);
    // mean over rows of tanh(pre + b1): C/D layout row=(q&3)+8*(q>>2)+4*kq, col=ln
    float b1v0 = b1[ln], b1v1 = b1[32 + ln], b1v2 = b1[64 + ln], b1v3 = b1[96 + ln];
#define HPART(f, A, B1V) do { float hs = 0.f; \
    _Pragma("unroll") for (int q = 0; q < 16; ++q) { \
      int rl = (q & 3) + 8 * (q >> 2) + 4 * kq; \
      float tv = tanhf((A)[q] + (B1V)); \
      hs += ((wr * 32 + rl) < NR) ? tv : 0.f; } \
    hs += __shfl_xor(hs, 32, 64); \
    if (l < 32) hpart[w * 128 + (f) * 32 + ln] = hs; } while (0)
    HPART(0, acc0, b1v0); HPART(1, acc1, b1v1); HPART(2, acc2, b1v2); HPART(3, acc3, b1v3);
  }
  __syncthreads();
  if (tid < NH) {
    float v = hpart[tid] + hpart[128 + tid] + hpart[256 + tid] + hpart[384 + tid];
    hbarv[tid] = v * (1.0f / NR);
  }
  __syncthreads();
  // layer 2 folded through the mean: out = W2^T . hbar + b2  (all f32)
  if (tid < NC) {
    float s = b2[tid];
#pragma unroll 8
    for (int h = 0; h < NH; ++h) s += hbarv[h] * W2[h * NC + tid];
    out[b * NC + tid] = s;
  }
#undef COFF
#undef STORE_ACC
#undef ADD_ACC
#undef HPART
}

extern "C" void kernel_launch(void* const* d_in, const int* in_sizes, int n_in,
                              void* d_out, int out_size, void* d_ws, size_t ws_size,
                              hipStream_t stream) {
  (void)in_sizes; (void)n_in; (void)out_size; (void)ws_size;
  const int* x     = (const int*)d_in[0];
  const int* noise = (const int*)d_in[1];
  const float* W1  = (const float*)d_in[2];
  const float* b1  = (const float*)d_in[3];
  const float* W2  = (const float*)d_in[4];
  const float* b2  = (const float*)d_in[5];
  float* out = (float*)d_out;

  __hip_bfloat16* W1T = (__hip_bfloat16*)d_ws;

  prep_w1t<<<DP / 32, 256, 0, stream>>>(W1, W1T);
  fused_main<<<NB, 512, 0, stream>>>(x, noise, W1T, b1, W2, b2, out);
}

// Round 6
// 232.648 us; speedup vs baseline: 2.6413x; 2.6413x over previous
//
#include <hip/hip_runtime.h>
#include <hip/hip_bf16.h>

#define NB 256
#define NR 100
#define NRH 50             // rows per block (half)
#define ND 6168
#define DP 6176            // ND padded to multiple of 32
#define NH 128
#define NC 100
#define KSTEP 32
#define NSTEP (DP / KSTEP) // 193
#define MT 64              // staged row tile (50 padded)
#define W1T_BYTES ((size_t)NH * DP * 2)

typedef __attribute__((ext_vector_type(8))) __bf16 bf16x8;
typedef __attribute__((ext_vector_type(4))) float f32x4;
typedef __attribute__((ext_vector_type(4))) int i32x4;
typedef __attribute__((ext_vector_type(4))) unsigned int u32x4;

// Non-draining-ish barrier (R3-proven): LDS ordering + barrier.
#define BAR() do { asm volatile("s_waitcnt lgkmcnt(0)" ::: "memory"); \
                   __builtin_amdgcn_s_barrier(); } while (0)

// ---------- prep: W1 (ND,NH) f32 -> W1T (NH, DP) bf16, zero-padded ----------
__global__ void prep_w1t(const float* __restrict__ W1, __hip_bfloat16* __restrict__ W1T) {
  __shared__ float tile[KSTEP][NH + 1];
  const int d0 = blockIdx.x * KSTEP;
  const int t = threadIdx.x;
#pragma unroll
  for (int p = 0; p < (KSTEP * NH) / 256; ++p) {
    int idx = p * 256 + t;
    int dd = idx >> 7;
    int h  = idx & 127;
    int d  = d0 + dd;
    tile[dd][h] = (d < ND) ? W1[d * NH + h] : 0.f;
  }
  __syncthreads();
#pragma unroll
  for (int p = 0; p < (KSTEP * NH) / 256; ++p) {
    int idx = p * 256 + t;
    int h  = idx >> 5;
    int dd = idx & 31;
    W1T[h * DP + d0 + dd] = __float2bfloat16(tile[dd][h]);
  }
}

// ---------- main: grid 512, block bid -> (b = bid>>1, half = bid&1), 256 thr ----------
// LDS (bytes):
//   [0, 12352)      xpair: 3088 dwords
//   [12352, 27712)  BF0: A [64 x 80B] @ +0 (5120), B [128 x 80B] @ +5120 (10240)
//   [27712, 43072)  BF1
__launch_bounds__(256, 2)
__global__ void fused_main(const int* __restrict__ x,
                           const int* __restrict__ noise,
                           const __hip_bfloat16* __restrict__ W1T,
                           const float* __restrict__ b1,
                           float* __restrict__ partials) {
  __shared__ __align__(16) char lds[43072];
  unsigned int* xpair = (unsigned int*)lds;
  char* const BF0 = lds + 12352;
  char* const BF1 = BF0 + 15360;

  const int tid  = threadIdx.x;
  const int lane = tid & 63;
  const int w    = tid >> 6;       // wave 0..3 (owns h-cols w*32..w*32+31)
  const int lq   = lane >> 4;
  const int lm   = lane & 15;
  const int bid  = blockIdx.x;
  const int b    = bid >> 1;
  const int half = bid & 1;

  // A staging: thread t -> row ar = t>>2 (0..63), k-quarter kc = t&3 (32B)
  const int ar = tid >> 2;
  const int kc = tid & 3;
  const int grow = half * NRH + ((ar < NRH) ? ar : (NRH - 1));  // clamped
  const int* nrow = noise + (size_t)b * NR * ND + (size_t)grow * ND;

  // B staging: thread t -> row br = t>>1 (0..127), half bh = t&1 (32B)
  const int br = tid >> 1;
  const int bh = tid & 1;
  const char* bsrc = (const char*)W1T + (size_t)br * DP * 2 + bh * 32;

  f32x4 acc[4][2] = {};

  auto ISSUE = [&](int s, i32x4* ra, i32x4* rb) {
    i32x4 z = {0, 0, 0, 0};
    const int k0 = s * KSTEP + kc * 8;
    ra[0] = (k0 + 4 <= ND) ? *(const i32x4*)(nrow + k0)     : z;
    ra[1] = (k0 + 8 <= ND) ? *(const i32x4*)(nrow + k0 + 4) : z;
    const long o = (long)s * 64;
    rb[0] = *(const i32x4*)(bsrc + o);
    rb[1] = *(const i32x4*)(bsrc + o + 16);
  };

  auto STORE = [&](int s, const i32x4* ra, const i32x4* rb, char* buf) {
    u32x4 xp = *(const u32x4*)(xpair + s * 16 + kc * 4);
    unsigned pk[4];
#pragma unroll
    for (int p = 0; p < 4; ++p) {
      unsigned n0 = (unsigned)ra[p >> 1][(p & 1) * 2];
      unsigned n1 = (unsigned)ra[p >> 1][(p & 1) * 2 + 1];
      pk[p] = ((n0 | (n1 << 16)) ^ xp[p]) * 0x3F80u;
    }
    u32x4 t = {pk[0], pk[1], pk[2], pk[3]};
    *(u32x4*)(buf + ar * 80 + kc * 16) = t;                  // A packed bf16
    *(i32x4*)(buf + 5120 + br * 80 + bh * 32)      = rb[0];  // B raw bf16
    *(i32x4*)(buf + 5120 + br * 80 + bh * 32 + 16) = rb[1];
  };

  auto COMPUTE = [&](const char* buf) {
    const char* Bb = buf + 5120;
    bf16x8 bf0 = *(const bf16x8*)(Bb + (w * 32 + lm) * 80 + lq * 16);
    bf16x8 bf1 = *(const bf16x8*)(Bb + (w * 32 + 16 + lm) * 80 + lq * 16);
#pragma unroll
    for (int mf = 0; mf < 4; ++mf) {
      bf16x8 af = *(const bf16x8*)(buf + (mf * 16 + lm) * 80 + lq * 16);
      acc[mf][0] = __builtin_amdgcn_mfma_f32_16x16x32_bf16(af, bf0, acc[mf][0], 0, 0, 0);
      acc[mf][1] = __builtin_amdgcn_mfma_f32_16x16x32_bf16(af, bf1, acc[mf][1], 0, 0, 0);
    }
  };

  i32x4 raA[2], rbA[2], raB[2], rbB[2];

  // ---- prologue ----
  ISSUE(0, raA, rbA);
  ISSUE(1, raB, rbB);
  {
    const int* xb = x + b * ND;
    for (int i = tid; i < DP / 2; i += 256) {
      unsigned p = 0;
      if (2 * i + 1 < ND) {
        int2 v = *(const int2*)(xb + 2 * i);
        p = ((unsigned)v.x & 1u) | (((unsigned)v.y & 1u) << 16);
      }
      xpair[i] = p;
    }
  }
  BAR();
  STORE(0, raA, rbA, BF0);
  ISSUE(2, raA, rbA);
  BAR();

  // ---- main loop: even tiles -> BF0/slotA, odd -> BF1/slotB ----
  for (int s = 0; s < NSTEP; s += 2) {
    COMPUTE(BF0);
    if (s + 1 < NSTEP) STORE(s + 1, raB, rbB, BF1);
    if (s + 3 < NSTEP) ISSUE(s + 3, raB, rbB);
    BAR();
    if (s + 1 < NSTEP) {
      COMPUTE(BF1);
      if (s + 2 < NSTEP) STORE(s + 2, raA, rbA, BF0);
      if (s + 4 < NSTEP) ISSUE(s + 4, raA, rbA);
      BAR();
    }
  }

  // ---- epilogue: masked tanh row-sum per h-column -> partials[bid][128] ----
  // C/D layout: row m = mf*16 + lq*4 + rg, col = wave-owned (w*32 + nf*16 + lm)
#pragma unroll
  for (int nf = 0; nf < 2; ++nf) {
    int hcol = w * 32 + nf * 16 + lm;
    float bb = b1[hcol];
    float ssum = 0.f;
#pragma unroll
    for (int mf = 0; mf < 4; ++mf) {
#pragma unroll
      for (int rg = 0; rg < 4; ++rg) {
        int m = mf * 16 + lq * 4 + rg;
        float tv = tanhf(acc[mf][nf][rg] + bb);
        ssum += (m < NRH) ? tv : 0.f;
      }
    }
    ssum += __shfl_xor(ssum, 16, 64);
    ssum += __shfl_xor(ssum, 32, 64);
    if (lq == 0) partials[(size_t)bid * NH + hcol] = ssum;
  }
}

// ---------- combine: out[b][c] = b2[c] + sum_h hbar[h] * W2[h][c] ----------
__global__ void combine(const float* __restrict__ partials,
                        const float* __restrict__ W2,
                        const float* __restrict__ b2,
                        float* __restrict__ out) {
  __shared__ float hbar[NH];
  const int b = blockIdx.x;
  const int t = threadIdx.x;   // 128 threads
  if (t < NH)
    hbar[t] = (partials[(size_t)(2 * b) * NH + t] + partials[(size_t)(2 * b + 1) * NH + t]) * (1.0f / NR);
  __syncthreads();
  if (t < NC) {
    float s = b2[t];
#pragma unroll 8
    for (int h = 0; h < NH; ++h) s += hbar[h] * W2[h * NC + t];
    out[b * NC + t] = s;
  }
}

extern "C" void kernel_launch(void* const* d_in, const int* in_sizes, int n_in,
                              void* d_out, int out_size, void* d_ws, size_t ws_size,
                              hipStream_t stream) {
  (void)in_sizes; (void)n_in; (void)out_size; (void)ws_size;
  const int* x     = (const int*)d_in[0];
  const int* noise = (const int*)d_in[1];
  const float* W1  = (const float*)d_in[2];
  const float* b1  = (const float*)d_in[3];
  const float* W2  = (const float*)d_in[4];
  const float* b2  = (const float*)d_in[5];
  float* out = (float*)d_out;

  __hip_bfloat16* W1T = (__hip_bfloat16*)d_ws;
  float* partials = (float*)((char*)d_ws + W1T_BYTES);

  prep_w1t<<<DP / KSTEP, 256, 0, stream>>>(W1, W1T);
  fused_main<<<2 * NB, 256, 0, stream>>>(x, noise, W1T, b1, partials);
  combine<<<NB, 128, 0, stream>>>(partials, W2, b2, out);
}

// Round 7
// 211.894 us; speedup vs baseline: 2.9000x; 1.0979x over previous
//
#include <hip/hip_runtime.h>
#include <hip/hip_bf16.h>

#define NB 256
#define NR 100
#define NRH 50             // rows per block (half of NR)
#define ND 6168
#define DP 6272            // ND padded to multiple of 128
#define NH 128
#define NC 100
#define NSUP (DP / 128)    // 49 superphases of K=128 ints
#define W1T_BYTES ((size_t)NH * DP * 2)

typedef __attribute__((ext_vector_type(8))) __bf16 bf16x8;
typedef __attribute__((ext_vector_type(4))) float f32x4;
typedef __attribute__((ext_vector_type(4))) int i32x4;
typedef __attribute__((ext_vector_type(4))) unsigned int u32x4;
typedef unsigned int u32;

typedef const __attribute__((address_space(1))) u32* gas_ptr;
typedef __attribute__((address_space(3))) u32* las_ptr;

__device__ __forceinline__ void gload16(const void* g, void* l) {
  __builtin_amdgcn_global_load_lds((gas_ptr)g, (las_ptr)l, 16, 0, 0);
}

// Counted-wait barrier (m201 pattern): wait own stage DMAs (vmcnt<=N), then
// rendezvous. No drain: later-issued loads stay in flight. sched_barrier(0)
// pins ordering (guide rule #18).
#define VBAR(N) do { \
  __builtin_amdgcn_sched_barrier(0); \
  asm volatile("s_waitcnt vmcnt(" #N ")"); \
  __builtin_amdgcn_sched_barrier(0); \
  __builtin_amdgcn_s_barrier(); \
  __builtin_amdgcn_sched_barrier(0); \
} while (0)

// ---------- prep: W1 (ND,NH) f32 -> W1T (NH, DP) bf16, zero-padded ----------
__global__ void prep_w1t(const float* __restrict__ W1, __hip_bfloat16* __restrict__ W1T) {
  __shared__ float tile[32][NH + 1];
  const int d0 = blockIdx.x * 32;
  const int t = threadIdx.x;
#pragma unroll
  for (int p = 0; p < 16; ++p) {
    int idx = p * 256 + t;
    int dd = idx >> 7;
    int h  = idx & 127;
    int d  = d0 + dd;
    tile[dd][h] = (d < ND) ? W1[d * NH + h] : 0.f;
  }
  __syncthreads();
#pragma unroll
  for (int p = 0; p < 16; ++p) {
    int idx = p * 256 + t;
    int h  = idx >> 5;
    int dd = idx & 31;
    W1T[h * DP + d0 + dd] = __float2bfloat16(tile[dd][h]);
  }
}

// ---------- main: grid 512 (b = bid>>1, half = bid&1), 256 threads ----------
// LDS: [0,12544) xpair; [12544,45312) A0 [64 rows][512B]; [45312,78080) A1.
// A staged RAW (int32) via global_load_lds, source pre-swizzled slot^=(row&7);
// XOR+bf16-pack happens per-fragment in the consumer. W1T frags: L2-hot
// register loads, double-buffered one superphase ahead.
__launch_bounds__(256, 2)
__global__ void fused_main(const int* __restrict__ x,
                           const int* __restrict__ noise,
                           const __hip_bfloat16* __restrict__ W1T,
                           const float* __restrict__ b1,
                           float* __restrict__ partials) {
  __shared__ __align__(16) char lds[78080];
  u32* xpair = (u32*)lds;
  char* const A0 = lds + 12544;
  char* const A1 = A0 + 32768;

  const int tid  = threadIdx.x;
  const int lane = tid & 63;
  const int w    = tid >> 6;       // wave 0..3 (owns h-cols w*32..w*32+31)
  const int lq   = lane >> 4;
  const int lm   = lane & 15;
  const int bid  = blockIdx.x;
  const int b    = bid >> 1;
  const int half = bid & 1;

  const size_t nbase = (size_t)b * NR * ND;

  f32x4 acc[4][2] = {};

  struct Bregs { bf16x8 f[8]; };   // [kt*2+nf], statically indexed
  Bregs B0r, B1r;

  // ---- stage superphase s noise into LDS buf (8 DMA calls per thread) ----
  auto STAGE = [&](int s, char* dst) {
#pragma unroll
    for (int i = 0; i < 8; ++i) {
      const int call = w * 8 + i;                 // 0..31 (wave-uniform)
      const int row  = call * 2 + (lane >> 5);    // staged row 0..63
      const int gr   = half * NRH + ((row < NRH) ? row : (NRH - 1));
      const int slot = lane & 31;
      const int slotp = slot ^ (row & 7);         // inverse swizzle on source
      int kint = s * 128 + slotp * 4;
      kint = (kint + 4 <= ND) ? kint : 0;         // clamp; B=0 masks garbage
      gload16(noise + nbase + (size_t)gr * ND + kint, dst + call * 1024);
    }
  };

  // ---- load W1T fragments for superphase s into registers ----
  auto BLOAD = [&](int s, Bregs& Br) {
#pragma unroll
    for (int kt = 0; kt < 4; ++kt)
#pragma unroll
      for (int nf = 0; nf < 2; ++nf)
        Br.f[kt * 2 + nf] = *(const bf16x8*)(W1T + (size_t)(w * 32 + nf * 16 + lm) * DP
                                             + s * 128 + kt * 32 + lq * 8);
  };

  // ---- consume superphase s: 4 k-tiles of 32, transform-in-register ----
  auto COMPUTE = [&](int s, const char* Ab, const Bregs& Br) {
#pragma unroll
    for (int kt = 0; kt < 4; ++kt) {
      u32x4 xp = *(const u32x4*)(xpair + s * 64 + kt * 16 + lq * 4);
#pragma unroll
      for (int mf = 0; mf < 4; ++mf) {
        const int row = mf * 16 + lm;
        const int s0  = kt * 8 + lq * 2;
        const char* base = Ab + row * 512;
        i32x4 v0 = *(const i32x4*)(base + ((s0    ) ^ (row & 7)) * 16);
        i32x4 v1 = *(const i32x4*)(base + ((s0 + 1) ^ (row & 7)) * 16);
        u32 pk0 = (((u32)v0[0] | ((u32)v0[1] << 16)) ^ xp[0]) * 0x3F80u;
        u32 pk1 = (((u32)v0[2] | ((u32)v0[3] << 16)) ^ xp[1]) * 0x3F80u;
        u32 pk2 = (((u32)v1[0] | ((u32)v1[1] << 16)) ^ xp[2]) * 0x3F80u;
        u32 pk3 = (((u32)v1[2] | ((u32)v1[3] << 16)) ^ xp[3]) * 0x3F80u;
        u32x4 pkv = {pk0, pk1, pk2, pk3};
        bf16x8 af = *(bf16x8*)&pkv;
        acc[mf][0] = __builtin_amdgcn_mfma_f32_16x16x32_bf16(af, Br.f[kt * 2 + 0], acc[mf][0], 0, 0, 0);
        acc[mf][1] = __builtin_amdgcn_mfma_f32_16x16x32_bf16(af, Br.f[kt * 2 + 1], acc[mf][1], 0, 0, 0);
      }
    }
  };

  // ---- prologue: stage super 0, fill xpair, one full-drain sync ----
  STAGE(0, A0);
  BLOAD(0, B0r);
  {
    const int* xb = x + b * ND;
    for (int i = tid; i < DP / 2; i += 256) {
      unsigned p = 0;
      if (2 * i + 1 < ND) {
        int2 v = *(const int2*)(xb + 2 * i);
        p = ((unsigned)v.x & 1u) | (((unsigned)v.y & 1u) << 16);
      }
      xpair[i] = p;
    }
  }
  __syncthreads();   // one-time drain; xpair + stage(0) visible

  // ---- main loop: 24 iters x 2 supers + tail. Counted vmcnt, no drain. ----
  for (int s = 0; s < NSUP - 1; s += 2) {
    VBAR(8);                                   // stage(s) landed (all waves)
    STAGE(s + 1, A1);
    BLOAD(s + 1, B1r);
    COMPUTE(s, A0, B0r);

    VBAR(8);                                   // stage(s+1) landed
    if (s + 2 < NSUP) { STAGE(s + 2, A0); BLOAD(s + 2, B0r); }
    COMPUTE(s + 1, A1, B1r);
  }
  VBAR(8);
  COMPUTE(NSUP - 1, A0, B0r);                  // super 48

  // ---- epilogue: masked tanh row-sum per h-column -> partials[bid][128] ----
#pragma unroll
  for (int nf = 0; nf < 2; ++nf) {
    int hcol = w * 32 + nf * 16 + lm;
    float bb = b1[hcol];
    float ssum = 0.f;
#pragma unroll
    for (int mf = 0; mf < 4; ++mf) {
#pragma unroll
      for (int rg = 0; rg < 4; ++rg) {
        int m = mf * 16 + lq * 4 + rg;
        float tv = tanhf(acc[mf][nf][rg] + bb);
        ssum += (m < NRH) ? tv : 0.f;
      }
    }
    ssum += __shfl_xor(ssum, 16, 64);
    ssum += __shfl_xor(ssum, 32, 64);
    if (lq == 0) partials[(size_t)bid * NH + hcol] = ssum;
  }
}

// ---------- combine: out[b][c] = b2[c] + sum_h hbar[h] * W2[h][c] ----------
__global__ void combine(const float* __restrict__ partials,
                        const float* __restrict__ W2,
                        const float* __restrict__ b2,
                        float* __restrict__ out) {
  __shared__ float hbar[NH];
  const int b = blockIdx.x;
  const int t = threadIdx.x;   // 128 threads
  if (t < NH)
    hbar[t] = (partials[(size_t)(2 * b) * NH + t] + partials[(size_t)(2 * b + 1) * NH + t]) * (1.0f / NR);
  __syncthreads();
  if (t < NC) {
    float s = b2[t];
#pragma unroll 8
    for (int h = 0; h < NH; ++h) s += hbar[h] * W2[h * NC + t];
    out[b * NC + t] = s;
  }
}

extern "C" void kernel_launch(void* const* d_in, const int* in_sizes, int n_in,
                              void* d_out, int out_size, void* d_ws, size_t ws_size,
                              hipStream_t stream) {
  (void)in_sizes; (void)n_in; (void)out_size; (void)ws_size;
  const int* x     = (const int*)d_in[0];
  const int* noise = (const int*)d_in[1];
  const float* W1  = (const float*)d_in[2];
  const float* b1  = (const float*)d_in[3];
  const float* W2  = (const float*)d_in[4];
  const float* b2  = (const float*)d_in[5];
  float* out = (float*)d_out;

  __hip_bfloat16* W1T = (__hip_bfloat16*)d_ws;
  float* partials = (float*)((char*)d_ws + W1T_BYTES);

  prep_w1t<<<DP / 32, 256, 0, stream>>>(W1, W1T);
  fused_main<<<2 * NB, 256, 0, stream>>>(x, noise, W1T, b1, partials);
  combine<<<NB, 128, 0, stream>>>(partials, W2, b2, out);
}

// Round 8
// 211.528 us; speedup vs baseline: 2.9050x; 1.0017x over previous
//
#include <hip/hip_runtime.h>
#include <hip/hip_bf16.h>

#define NB 256
#define NR 100
#define ND 6168
#define DP 6272            // padded to 98 * 64
#define NH 128
#define NC 100
#define NSEG 98            // segments of K=64 ints
#define ABUF 32768         // 128 rows x 256 B
#define ROWB 24672         // ND*4 bytes per noise row
#define W1T_BYTES ((size_t)NH * DP * 2)

typedef __attribute__((ext_vector_type(8))) __bf16 bf16x8;
typedef __attribute__((ext_vector_type(4))) float f32x4;
typedef __attribute__((ext_vector_type(4))) int i32x4;
typedef __attribute__((ext_vector_type(4))) unsigned int u32x4;
typedef unsigned int u32;

typedef const __attribute__((address_space(1))) u32* gas_ptr;
typedef __attribute__((address_space(3))) u32* las_ptr;

__device__ __forceinline__ void gload16(const void* g, void* l) {
  __builtin_amdgcn_global_load_lds((gas_ptr)g, (las_ptr)l, 16, 0, 0);
}

#define SB() __builtin_amdgcn_sched_barrier(0)
// Barrier guaranteeing stage(s) landed: exactly 16 vmem ops are issued after
// stage(s) in steady state (bload(s-1)4, stage(s+1)4, bload(s)4, stage(s+2)4),
// so vmcnt(16) retires stage(s). lgkmcnt(0) orders LDS before rendezvous.
#define VBAR16() do { SB(); asm volatile("s_waitcnt vmcnt(16)"); SB(); \
  asm volatile("s_waitcnt lgkmcnt(0)"); SB(); __builtin_amdgcn_s_barrier(); SB(); } while (0)

// ---------- prep: W1 (ND,NH) f32 -> W1T (NH, DP) bf16, zero-padded ----------
__global__ void prep_w1t(const float* __restrict__ W1, __hip_bfloat16* __restrict__ W1T) {
  __shared__ float tile[32][NH + 1];
  const int d0 = blockIdx.x * 32;
  const int t = threadIdx.x;
#pragma unroll
  for (int p = 0; p < 16; ++p) {
    int idx = p * 256 + t;
    int dd = idx >> 7;
    int h  = idx & 127;
    int d  = d0 + dd;
    tile[dd][h] = (d < ND) ? W1[d * NH + h] : 0.f;
  }
  __syncthreads();
#pragma unroll
  for (int p = 0; p < 16; ++p) {
    int idx = p * 256 + t;
    int h  = idx >> 5;
    int dd = idx & 31;
    W1T[h * DP + d0 + dd] = __float2bfloat16(tile[dd][h]);
  }
}

// ---------- main: one block per b, 512 threads (8 waves, 2/SIMD) ----------
// LDS: [0,12544) xpair; [12544, 12544+4*32768) A buffers (4-deep rotation).
// Epilogue overlay at 0: hpart [2][128] f32, hbar [128] f32 at +1024.
__launch_bounds__(512, 2)
__global__ void fused_main(const int* __restrict__ x,
                           const int* __restrict__ noise,
                           const __hip_bfloat16* __restrict__ W1T,
                           const float* __restrict__ b1,
                           const float* __restrict__ W2,
                           const float* __restrict__ b2,
                           float* __restrict__ out) {
  __shared__ __align__(16) char lds[12544 + 4 * ABUF];
  u32* xpair = (u32*)lds;
  char* const Ab = lds + 12544;

  const int tid  = threadIdx.x;
  const int lane = tid & 63;
  const int w    = tid >> 6;      // 0..7
  const int wm   = w >> 2;        // row half (64 rows)
  const int wn   = w & 3;         // col quarter (32 h-cols)
  const int lq   = lane >> 4;
  const int lm   = lane & 15;
  const int b    = blockIdx.x;

  // ---- per-thread invariant staging descriptors (4 DMA calls/segment) ----
  const char* nsrc[4];   // global base (row + swizzled slot), seg 0
  u32 offmax[4];         // per-lane clamp so reads stay inside the row
  int dofs[4];           // LDS byte offset within an A buffer
  {
    const size_t nb = (size_t)b * NR * ND;
#pragma unroll
    for (int i = 0; i < 4; ++i) {
      int c   = w * 4 + i;              // call 0..31, covers rows 4c..4c+3
      int row = c * 4 + (lane >> 4);    // staged row 0..127
      int gr  = (row < NR) ? row : (NR - 1);
      int sg  = (lane & 15) ^ (row & 7);    // swizzled source slot
      nsrc[i]   = (const char*)(noise + nb + (size_t)gr * ND) + sg * 16;
      offmax[i] = (u32)(ROWB - 16 - sg * 16);
      dofs[i]   = c * 1024;             // + lane*16 applied by hardware
    }
  }
  const __hip_bfloat16* wsrc0 = W1T + (size_t)(wn * 32 + lm) * DP + lq * 8;
  const __hip_bfloat16* wsrc1 = W1T + (size_t)(wn * 32 + 16 + lm) * DP + lq * 8;

  f32x4 acc[4][2] = {};
  struct Bregs { bf16x8 f[4]; };   // [kt*2+nf], statically indexed
  Bregs Bcur, Bnxt;

  auto STAGE = [&](int ss, int bufidx) {
    char* dstb = Ab + bufidx * ABUF;
    const u32 off = (u32)(ss * 256);
#pragma unroll
    for (int i = 0; i < 4; ++i) {
      u32 o = (off > offmax[i]) ? offmax[i] : off;   // tail clamp (garbage -> B=0 cols)
      gload16(nsrc[i] + o, dstb + dofs[i]);
    }
  };

  auto BLOAD = [&](int s, Bregs& Br) {
#pragma unroll
    for (int kt = 0; kt < 2; ++kt) {
      Br.f[kt * 2 + 0] = *(const bf16x8*)(wsrc0 + s * 64 + kt * 32);
      Br.f[kt * 2 + 1] = *(const bf16x8*)(wsrc1 + s * 64 + kt * 32);
    }
  };

  auto COMPUTE = [&](int s, const char* A, const Bregs& Br) {
#pragma unroll
    for (int kt = 0; kt < 2; ++kt) {
      u32x4 xp = *(const u32x4*)(xpair + s * 32 + kt * 16 + lq * 4);
#pragma unroll
      for (int mf = 0; mf < 4; ++mf) {
        const int row  = wm * 64 + mf * 16 + lm;
        const int off0 = row * 256 + (((kt * 8 + lq * 2) ^ (row & 7)) * 16);
        i32x4 v0 = *(const i32x4*)(A + off0);
        i32x4 v1 = *(const i32x4*)(A + (off0 ^ 16));
        u32 q0 = (((u32)v0[0] | ((u32)v0[1] << 16)) ^ xp[0]) * 0x3F80u;
        u32 q1 = (((u32)v0[2] | ((u32)v0[3] << 16)) ^ xp[1]) * 0x3F80u;
        u32 q2 = (((u32)v1[0] | ((u32)v1[1] << 16)) ^ xp[2]) * 0x3F80u;
        u32 q3 = (((u32)v1[2] | ((u32)v1[3] << 16)) ^ xp[3]) * 0x3F80u;
        u32x4 pkv = {q0, q1, q2, q3};
        bf16x8 af = *(bf16x8*)&pkv;
        acc[mf][0] = __builtin_amdgcn_mfma_f32_16x16x32_bf16(af, Br.f[kt * 2 + 0], acc[mf][0], 0, 0, 0);
        acc[mf][1] = __builtin_amdgcn_mfma_f32_16x16x32_bf16(af, Br.f[kt * 2 + 1], acc[mf][1], 0, 0, 0);
      }
    }
  };

  // ---- prologue: stage 3 segments deep, bload(0), fill xpair, full drain ----
  STAGE(0, 0);
  STAGE(1, 1);
  STAGE(2, 2);
  BLOAD(0, Bcur);
  {
    const int* xb = x + b * ND;
    for (int i = tid; i < DP / 2; i += 512) {
      u32 p = 0;
      if (2 * i + 1 < ND) {
        int2 v = *(const int2*)(xb + 2 * i);
        p = ((u32)v.x & 1u) | (((u32)v.y & 1u) << 16);
      }
      xpair[i] = p;
    }
  }
  __syncthreads();   // one-time full drain; xpair + stage(0..2) visible

  // ---- main loop: 49 iters x 2 segments; counted waits, no drains ----
#pragma unroll 1
  for (int s = 0; s < NSEG; s += 2) {
    {
      VBAR16();
      int sn = (s + 1 < NSEG) ? (s + 1) : (NSEG - 1);
      BLOAD(sn, Bnxt);
      SB();
      int sc = (s + 3 < NSEG) ? (s + 3) : (NSEG - 1);
      STAGE(sc, (s + 3) & 3);
      SB();
      COMPUTE(s, Ab + (s & 3) * ABUF, Bcur);
    }
    {
      VBAR16();
      int sn = (s + 2 < NSEG) ? (s + 2) : (NSEG - 1);
      BLOAD(sn, Bcur);
      SB();
      int sc = (s + 4 < NSEG) ? (s + 4) : (NSEG - 1);
      STAGE(sc, (s + 4) & 3);
      SB();
      COMPUTE(s + 1, Ab + ((s + 1) & 3) * ABUF, Bnxt);
    }
  }

  // ---- epilogue: mean over rows of tanh(acc + b1), then W2^T fold ----
  __syncthreads();
  float* hpart = (float*)lds;            // [2][128]
  float* hbar  = (float*)(lds + 1024);   // [128]
#pragma unroll
  for (int nf = 0; nf < 2; ++nf) {
    int hcol = wn * 32 + nf * 16 + lm;
    float bb = b1[hcol];
    float ssum = 0.f;
#pragma unroll
    for (int mf = 0; mf < 4; ++mf) {
#pragma unroll
      for (int rg = 0; rg < 4; ++rg) {
        int m = wm * 64 + mf * 16 + lq * 4 + rg;
        float tv = tanhf(acc[mf][nf][rg] + bb);
        ssum += (m < NR) ? tv : 0.f;
      }
    }
    ssum += __shfl_xor(ssum, 16, 64);
    ssum += __shfl_xor(ssum, 32, 64);
    if (lq == 0) hpart[wm * 128 + hcol] = ssum;
  }
  __syncthreads();
  if (tid < NH) hbar[tid] = (hpart[tid] + hpart[128 + tid]) * (1.0f / NR);
  __syncthreads();
  if (tid < NC) {
    float sacc = b2[tid];
#pragma unroll 8
    for (int h = 0; h < NH; ++h) sacc += hbar[h] * W2[h * NC + tid];
    out[b * NC + tid] = sacc;
  }
}

extern "C" void kernel_launch(void* const* d_in, const int* in_sizes, int n_in,
                              void* d_out, int out_size, void* d_ws, size_t ws_size,
                              hipStream_t stream) {
  (void)in_sizes; (void)n_in; (void)out_size; (void)ws_size;
  const int* x     = (const int*)d_in[0];
  const int* noise = (const int*)d_in[1];
  const float* W1  = (const float*)d_in[2];
  const float* b1  = (const float*)d_in[3];
  const float* W2  = (const float*)d_in[4];
  const float* b2  = (const float*)d_in[5];
  float* out = (float*)d_out;

  __hip_bfloat16* W1T = (__hip_bfloat16*)d_ws;

  prep_w1t<<<DP / 32, 256, 0, stream>>>(W1, W1T);
  fused_main<<<NB, 512, 0, stream>>>(x, noise, W1T, b1, W2, b2, out);
}